// Round 9
// baseline (176.384 us; speedup 1.0000x reference)
//
#include <hip/hip_runtime.h>
#include <math.h>

namespace {

constexpr int NQ = 10;
constexpr int NL = 4;
constexpr float PI_F = 3.14159265358979323846f;

// TWO batch elements per wave, interleaved as independent register states
// (sA[16], sB[16] of packed {re,im} float2) -> 2x independent dependency
// chains per wave for latency hiding. Complex math via v_pk_fma_f32
// op_sel/neg_lo (2 pk per complex mul/fma). Lane exchanges: DPP for xor
// masks 1,2,8; ds_swizzle for 4,16; layer-trailing C(9->0) deferred into
// next layer's wire-0 gate (xor-32). Layer 0 exploits |0> start: its ten
// single-qubit gates yield a PRODUCT state, built directly from column-0
// factors (~33 cmul) instead of full gate application (no exchanges at all).

typedef float v2 __attribute__((ext_vector_type(2)));

__device__ __forceinline__ float readlane_f(float v, int lane_const) {
  return __int_as_float(__builtin_amdgcn_readlane(__float_as_int(v), lane_const));
}
__device__ __forceinline__ float bperm_f(int addr4, float v) {
  return __int_as_float(__builtin_amdgcn_ds_bpermute(addr4, __float_as_int(v)));
}

// xor-lane exchange: DPP where possible (masks 1,2,8), else DS.
template<int MASK>
__device__ __forceinline__ float lxor(float v) {
  if constexpr (MASK == 1 || MASK == 2 || MASK == 8) {
    constexpr int ctrl = (MASK == 1) ? 0xB1 : (MASK == 2) ? 0x4E : 0x128;
    int i = __float_as_int(v);
    return __int_as_float(__builtin_amdgcn_update_dpp(i, i, ctrl, 0xF, 0xF, true));
  } else {
    return __shfl_xor(v, MASK, 64);
  }
}
template<int MASK>
__device__ __forceinline__ v2 lxor2(v2 v) {
  v2 r; r.x = lxor<MASK>(v.x); r.y = lxor<MASK>(v.y); return r;
}

// d = u (*) a   (complex multiply; packed {re,im})
__device__ __forceinline__ v2 cmul(v2 u, v2 a) {
  v2 d;
  asm("v_pk_mul_f32 %0, %1, %2 op_sel:[0,0] op_sel_hi:[0,1]\n\t"
      "v_pk_fma_f32 %0, %1, %2, %0 op_sel:[1,1,0] op_sel_hi:[1,0,1] neg_lo:[1,0,0]"
      : "=&v"(d) : "v"(u), "v"(a));
  return d;
}
// d = acc + u (*) a
__device__ __forceinline__ v2 cfma(v2 u, v2 a, v2 acc) {
  v2 d;
  asm("v_pk_fma_f32 %0, %1, %2, %3 op_sel:[0,0,0] op_sel_hi:[0,1,1]\n\t"
      "v_pk_fma_f32 %0, %1, %2, %0 op_sel:[1,1,0] op_sel_hi:[1,0,1] neg_lo:[1,0,0]"
      : "=&v"(d) : "v"(u), "v"(a), "v"(acc));
  return d;
}

struct SU2 { v2 u00, u01, u10, u11; };

// Gate on state bit P applied to BOTH states (interleaved for ILP).
// SWAP_ODD: pending xor-32 lane swap on odd regs consumed here (P==9 only).
template<int P, bool SW>
__device__ __forceinline__ void gate2(v2 (&a)[16], v2 (&b)[16],
                                      const SU2& A, const SU2& B, int lane) {
  if constexpr (P < 4) {
    constexpr int bit = 1 << P;
#pragma unroll
    for (int r = 0; r < 16; ++r) {
      if ((r & bit) == 0) {
        int r1 = r | bit;
        v2 a0 = a[r], a1 = a[r1];
        a[r]  = cfma(A.u01, a1, cmul(A.u00, a0));
        a[r1] = cfma(A.u11, a1, cmul(A.u10, a0));
        v2 b0 = b[r], b1 = b[r1];
        b[r]  = cfma(B.u01, b1, cmul(B.u00, b0));
        b[r1] = cfma(B.u11, b1, cmul(B.u10, b0));
      }
    }
  } else {
    constexpr int mask = 1 << (P - 4);
    bool hi = (lane & mask) != 0;
    v2 cAa = hi ? A.u11 : A.u00, cBa = hi ? A.u10 : A.u01;
    v2 cAb = hi ? B.u11 : B.u00, cBb = hi ? B.u10 : B.u01;
#pragma unroll
    for (int r = 0; r < 16; ++r) {
      v2 pa = lxor2<mask>(a[r]);
      v2 pb = lxor2<mask>(b[r]);
      if constexpr (SW) {
        if (r & 1) {
          a[r] = cfma(cAa, pa, cmul(cBa, a[r]));
          b[r] = cfma(cAb, pb, cmul(cBb, b[r]));
          continue;
        }
      }
      a[r] = cfma(cBa, pa, cmul(cAa, a[r]));
      b[r] = cfma(cBb, pb, cmul(cAb, b[r]));
    }
  }
}

// CNOT chain tail: (9,8)(8,7)(7,6)(6,5)(5,4) composed bpermute | (4,3)
// cndmask | (3,2)(2,1)(1,0) reg swaps | (0,9) DEFERRED.
__device__ __forceinline__ void cnot_block(v2 (&a)[16], v2 (&b)[16],
                                           int lane, int srcl4) {
#pragma unroll
  for (int r = 0; r < 16; ++r) {
    a[r].x = bperm_f(srcl4, a[r].x); a[r].y = bperm_f(srcl4, a[r].y);
    b[r].x = bperm_f(srcl4, b[r].x); b[r].y = bperm_f(srcl4, b[r].y);
  }
  bool ctrl = (lane & 1) != 0;
#pragma unroll
  for (int r = 0; r < 8; ++r) {
    int r1 = r | 8;
    v2 t0 = a[r], t1 = a[r1];
    a[r] = ctrl ? t1 : t0;  a[r1] = ctrl ? t0 : t1;
    t0 = b[r]; t1 = b[r1];
    b[r] = ctrl ? t1 : t0;  b[r1] = ctrl ? t0 : t1;
  }
#pragma unroll
  for (int r = 8; r < 12; ++r) {
    v2 t = a[r]; a[r] = a[r | 4]; a[r | 4] = t;
    t = b[r]; b[r] = b[r | 4]; b[r | 4] = t;
  }
  {
    const int rs[4] = {4, 5, 12, 13};
#pragma unroll
    for (int k = 0; k < 4; ++k) {
      int r = rs[k];
      v2 t = a[r]; a[r] = a[r | 2]; a[r | 2] = t;
      t = b[r]; b[r] = b[r | 2]; b[r | 2] = t;
    }
  }
#pragma unroll
  for (int r = 2; r < 16; r += 4) {
    v2 t = a[r]; a[r] = a[r | 1]; a[r | 1] = t;
    t = b[r]; b[r] = b[r | 1]; b[r | 1] = t;
  }
}

// Layer 0 on |0>: product state. Wire w (0..5) -> lane bit (5-w);
// wires 6..9 -> reg bits 3..0. amp = prod of column-0 entries.
__device__ __forceinline__ void init_product(v2 (&s)[16], const float4* wmat,
                                             float cx, float sx, int lane) {
  v2 u0, u1;
#define C0(i) { float4 wa = wmat[(i) * 2], wb = wmat[(i) * 2 + 1]; \
    v2 wa0 = {wa.x, wa.y}, wa1 = {wa.z, wa.w}; \
    v2 wb0 = {wb.x, wb.y}, wb1 = {wb.z, wb.w}; \
    float ca = readlane_f(cx, (i)), sa = readlane_f(sx, (i)); \
    u0 = ca * wa0 + sa * wa1; u1 = ca * wb0 + sa * wb1; }
  v2 f;
  C0(0); f = (lane & 32) ? u1 : u0;
  C0(1); f = cmul((lane & 16) ? u1 : u0, f);
  C0(2); f = cmul((lane & 8) ? u1 : u0, f);
  C0(3); f = cmul((lane & 4) ? u1 : u0, f);
  C0(4); f = cmul((lane & 2) ? u1 : u0, f);
  C0(5); f = cmul((lane & 1) ? u1 : u0, f);
  v2 q6_0, q6_1, q7_0, q7_1, q8_0, q8_1, q9_0, q9_1;
  C0(6); q6_0 = u0; q6_1 = u1;
  C0(7); q7_0 = u0; q7_1 = u1;
  C0(8); q8_0 = u0; q8_1 = u1;
  C0(9); q9_0 = u0; q9_1 = u1;
#undef C0
  // qa[(b1<<1)|b0] = v8[b1]*v9[b0] ; qb[(b3<<1)|b2] = v6[b3]*v7[b2]
  v2 qa0 = cmul(q8_0, q9_0), qa1 = cmul(q8_0, q9_1);
  v2 qa2 = cmul(q8_1, q9_0), qa3 = cmul(q8_1, q9_1);
  v2 qb0 = cmul(q6_0, q7_0), qb1 = cmul(q6_0, q7_1);
  v2 qb2 = cmul(q6_1, q7_0), qb3 = cmul(q6_1, q7_1);
  v2 fa0 = cmul(qa0, f), fa1 = cmul(qa1, f), fa2 = cmul(qa2, f), fa3 = cmul(qa3, f);
  s[0]  = cmul(qb0, fa0); s[1]  = cmul(qb0, fa1); s[2]  = cmul(qb0, fa2); s[3]  = cmul(qb0, fa3);
  s[4]  = cmul(qb1, fa0); s[5]  = cmul(qb1, fa1); s[6]  = cmul(qb1, fa2); s[7]  = cmul(qb1, fa3);
  s[8]  = cmul(qb2, fa0); s[9]  = cmul(qb2, fa1); s[10] = cmul(qb2, fa2); s[11] = cmul(qb2, fa3);
  s[12] = cmul(qb3, fa0); s[13] = cmul(qb3, fa1); s[14] = cmul(qb3, fa2); s[15] = cmul(qb3, fa3);
}

template<int L>
__device__ __forceinline__ void layer_gates(v2 (&sA)[16], v2 (&sB)[16],
                                            const float4* wmat,
                                            float cxA, float sxA,
                                            float cxB, float sxB, int lane) {
#define FUSED2(i, SW) { \
    float4 wa = wmat[(L * NQ + (i)) * 2], wb = wmat[(L * NQ + (i)) * 2 + 1]; \
    v2 wa0 = {wa.x, wa.y}, wa1 = {wa.z, wa.w}; \
    v2 wb0 = {wb.x, wb.y}, wb1 = {wb.z, wb.w}; \
    float caA = readlane_f(cxA, (i)), saA = readlane_f(sxA, (i)); \
    float caB = readlane_f(cxB, (i)), saB = readlane_f(sxB, (i)); \
    SU2 UA = { caA * wa0 + saA * wa1, caA * wa1 - saA * wa0, \
               caA * wb0 + saA * wb1, caA * wb1 - saA * wb0 }; \
    SU2 UB = { caB * wa0 + saB * wa1, caB * wa1 - saB * wa0, \
               caB * wb0 + saB * wb1, caB * wb1 - saB * wb0 }; \
    gate2<9 - (i), SW>(sA, sB, UA, UB, lane); }
  FUSED2(0, true)   // wire0 = xor-32 lane gate; consumes pending (0,9) swap
  FUSED2(1, false) FUSED2(2, false) FUSED2(3, false) FUSED2(4, false)
  FUSED2(5, false) FUSED2(6, false) FUSED2(7, false) FUSED2(8, false) FUSED2(9, false)
#undef FUSED2
}

__global__ __launch_bounds__(256, 5) void qsim(const float* __restrict__ x,
                                               const float* __restrict__ w,
                                               float* __restrict__ out, int batch) {
  // Batch-shared fused weight matrices W = RZ(w2)*RY(w1)*RZ(w0).
  __shared__ float4 wmat[NL * NQ * 2];
  int tid = threadIdx.x;
  if (tid < NL * NQ) {
    const float* wp = &w[tid * 3];
    float t0 = 0.5f * wp[0], t1 = 0.5f * wp[1], t2 = 0.5f * wp[2];
    float c1, s1; sincosf(t1, &s1, &c1);
    float cA, sA; sincosf(t0 + t2, &sA, &cA);
    float cB, sB; sincosf(t0 - t2, &sB, &cB);
    wmat[tid * 2]     = make_float4(c1 * cA, -c1 * sA, -s1 * cB, -s1 * sB);
    wmat[tid * 2 + 1] = make_float4(s1 * cB, -s1 * sB,  c1 * cA,  c1 * sA);
  }
  __syncthreads();

  int lane = tid & 63;
  int pairIdx = blockIdx.x * 4 + (tid >> 6);
  int bA = pairIdx * 2;
  if (bA >= batch) return;
  int bB = bA + 1;

  float cxA = 1.0f, sxA = 0.0f, cxB = 1.0f, sxB = 0.0f;
  if (lane < NQ) {
    float thA = tanhf(x[bA * NQ + lane]) * PI_F;
    sincosf(0.5f * thA, &sxA, &cxA);
    float thB = tanhf(x[bB * NQ + lane]) * PI_F;
    sincosf(0.5f * thB, &sxB, &cxB);
  }

  // Composed lane-permutation for the 5 lane-lane CNOTs.
  int srcl4;
  {
    int t = lane;
    t ^= (t >> 1) & 1;
    t ^= ((t >> 2) & 1) << 1;
    t ^= ((t >> 3) & 1) << 2;
    t ^= ((t >> 4) & 1) << 3;
    t ^= ((t >> 5) & 1) << 4;
    srcl4 = t << 2;
  }

  v2 sA[16], sB[16];
  // Layer 0 single-qubit part: direct product state (|0> start).
  init_product(sA, wmat, cxA, sxA, lane);
  init_product(sB, wmat, cxB, sxB, lane);
  cnot_block(sA, sB, lane, srcl4);

  layer_gates<1>(sA, sB, wmat, cxA, sxA, cxB, sxB, lane);
  cnot_block(sA, sB, lane, srcl4);
  layer_gates<2>(sA, sB, wmat, cxA, sxA, cxB, sxB, lane);
  cnot_block(sA, sB, lane, srcl4);
  layer_gates<3>(sA, sB, wmat, cxA, sxA, cxB, sxB, lane);
  cnot_block(sA, sB, lane, srcl4);
  // Layer 3's (0,9) still pending: odd regs' amps live at lane^32.

  // Measurement (per elem). q=0 sign fix for the pending swap: totE - totO.
  float partA[10], partB[10];
#pragma unroll
  for (int e = 0; e < 2; ++e) {
    v2 (&s)[16] = e ? sB : sA;
    float (&part)[10] = e ? partB : partA;
    float prob[16];
    float totE = 0.0f, totO = 0.0f;
#pragma unroll
    for (int r = 0; r < 16; ++r) {
      prob[r] = s[r].x * s[r].x + s[r].y * s[r].y;
      if (r & 1) totO += prob[r]; else totE += prob[r];
    }
    float total = totE + totO;
#pragma unroll
    for (int p = 0; p < 4; ++p) {
      float acc = 0.0f;
#pragma unroll
      for (int r = 0; r < 16; ++r)
        acc += (r & (1 << p)) ? -prob[r] : prob[r];
      part[p] = acc;
    }
#pragma unroll
    for (int p = 4; p < 9; ++p)
      part[p] = (lane & (1 << (p - 4))) ? -total : total;
    {
      float d = totE - totO;
      part[9] = (lane & 32) ? -d : d;
    }
#pragma unroll
    for (int p = 0; p < 10; ++p) {
      float a = part[p];
      a += lxor<1>(a);
      a += lxor<2>(a);
      a += lxor<4>(a);
      a += lxor<8>(a);
      a += lxor<16>(a);
      a += lxor<32>(a);
      part[p] = a;
    }
  }

  if (lane == 0) {
#pragma unroll
    for (int q = 0; q < NQ; ++q)
      out[bA * NQ + q] = partA[9 - q];
  }
  if (lane == 1) {
#pragma unroll
    for (int q = 0; q < NQ; ++q)
      out[bB * NQ + q] = partB[9 - q];
  }
}

}  // namespace

extern "C" void kernel_launch(void* const* d_in, const int* in_sizes, int n_in,
                              void* d_out, int out_size, void* d_ws, size_t ws_size,
                              hipStream_t stream) {
  const float* x = (const float*)d_in[0];
  const float* w = (const float*)d_in[1];
  float* out = (float*)d_out;
  int batch = in_sizes[0] / NQ;
  int pairs = (batch + 1) / 2;
  int blocks = (pairs + 3) / 4;  // 4 waves/block, 2 batch elements per wave
  qsim<<<blocks, 256, 0, stream>>>(x, w, out, batch);
}

// Round 10
// 169.731 us; speedup vs baseline: 1.0392x; 1.0392x over previous
//
#include <hip/hip_runtime.h>
#include <math.h>

namespace {

constexpr int NQ = 10;
constexpr int NL = 4;
constexpr float PI_F = 3.14159265358979323846f;

// One batch element per wave (R8 shape: VGPR 36, zero spill). Packed {re,im}
// float2 per amp; complex math via v_pk_fma_f32 op_sel/neg_lo. Lane
// exchanges: DPP for xor masks 1,2,8; ds_swizzle for 4,16. Layer-trailing
// C(9->0) deferred into next layer's wire-0 gate (xor-32); measurement
// fixes the final pending swap. Layer 0 exploits the |0> start: its ten
// single-qubit gates yield a PRODUCT state built from column-0 factors
// (~33 cmul, no exchanges) instead of full gate application.

typedef float v2 __attribute__((ext_vector_type(2)));

__device__ __forceinline__ float readlane_f(float v, int lane_const) {
  return __int_as_float(__builtin_amdgcn_readlane(__float_as_int(v), lane_const));
}
__device__ __forceinline__ float bperm_f(int addr4, float v) {
  return __int_as_float(__builtin_amdgcn_ds_bpermute(addr4, __float_as_int(v)));
}

// xor-lane exchange: DPP where possible (masks 1,2,8), else DS.
template<int MASK>
__device__ __forceinline__ float lxor(float v) {
  if constexpr (MASK == 1 || MASK == 2 || MASK == 8) {
    constexpr int ctrl = (MASK == 1) ? 0xB1 : (MASK == 2) ? 0x4E : 0x128;
    int i = __float_as_int(v);
    return __int_as_float(__builtin_amdgcn_update_dpp(i, i, ctrl, 0xF, 0xF, true));
  } else {
    return __shfl_xor(v, MASK, 64);
  }
}
template<int MASK>
__device__ __forceinline__ v2 lxor2(v2 v) {
  v2 r; r.x = lxor<MASK>(v.x); r.y = lxor<MASK>(v.y); return r;
}

// d = u (*) a   (complex multiply; packed {re,im})
__device__ __forceinline__ v2 cmul(v2 u, v2 a) {
  v2 d;
  asm("v_pk_mul_f32 %0, %1, %2 op_sel:[0,0] op_sel_hi:[0,1]\n\t"
      "v_pk_fma_f32 %0, %1, %2, %0 op_sel:[1,1,0] op_sel_hi:[1,0,1] neg_lo:[1,0,0]"
      : "=&v"(d) : "v"(u), "v"(a));
  return d;
}
// d = acc + u (*) a
__device__ __forceinline__ v2 cfma(v2 u, v2 a, v2 acc) {
  v2 d;
  asm("v_pk_fma_f32 %0, %1, %2, %3 op_sel:[0,0,0] op_sel_hi:[0,1,1]\n\t"
      "v_pk_fma_f32 %0, %1, %2, %0 op_sel:[1,1,0] op_sel_hi:[1,0,1] neg_lo:[1,0,0]"
      : "=&v"(d) : "v"(u), "v"(a), "v"(acc));
  return d;
}

// Gate on state bit P. SW: pending xor-32 lane swap on odd regs consumed
// here (only legal for P==9, mask 32).
template<int P, bool SW>
__device__ __forceinline__ void apply_u(v2 (&s)[16],
                                        v2 u00, v2 u01, v2 u10, v2 u11,
                                        int lane) {
  if constexpr (P < 4) {
    constexpr int bit = 1 << P;
#pragma unroll
    for (int r = 0; r < 16; ++r) {
      if ((r & bit) == 0) {
        int r1 = r | bit;
        v2 a0 = s[r], a1 = s[r1];
        s[r]  = cfma(u01, a1, cmul(u00, a0));
        s[r1] = cfma(u11, a1, cmul(u10, a0));
      }
    }
  } else {
    constexpr int mask = 1 << (P - 4);
    bool hi = (lane & mask) != 0;
    v2 cA = hi ? u11 : u00;   // own coefficient (clean layout)
    v2 cB = hi ? u10 : u01;   // partner coefficient
#pragma unroll
    for (int r = 0; r < 16; ++r) {
      v2 p = lxor2<mask>(s[r]);
      if constexpr (SW) {
        if (r & 1) { s[r] = cfma(cA, p, cmul(cB, s[r])); continue; }
      }
      s[r] = cfma(cB, p, cmul(cA, s[r]));
    }
  }
}

// CNOT chain: (9,8)(8,7)(7,6)(6,5)(5,4) composed bpermute | (4,3) cndmask |
// (3,2)(2,1)(1,0) reg swaps | (0,9) DEFERRED.
__device__ __forceinline__ void cnot_block(v2 (&s)[16], int lane, int srcl4) {
#pragma unroll
  for (int r = 0; r < 16; ++r) {
    s[r].x = bperm_f(srcl4, s[r].x);
    s[r].y = bperm_f(srcl4, s[r].y);
  }
  bool ctrl = (lane & 1) != 0;
#pragma unroll
  for (int r = 0; r < 8; ++r) {
    int r1 = r | 8;
    v2 t0 = s[r], t1 = s[r1];
    s[r]  = ctrl ? t1 : t0;
    s[r1] = ctrl ? t0 : t1;
  }
#pragma unroll
  for (int r = 8; r < 12; ++r) { v2 t = s[r]; s[r] = s[r | 4]; s[r | 4] = t; }
  {
    const int rs[4] = {4, 5, 12, 13};
#pragma unroll
    for (int k = 0; k < 4; ++k) {
      int r = rs[k];
      v2 t = s[r]; s[r] = s[r | 2]; s[r | 2] = t;
    }
  }
#pragma unroll
  for (int r = 2; r < 16; r += 4) { v2 t = s[r]; s[r] = s[r | 1]; s[r | 1] = t; }
}

// Layer 0 on |0>: product state. Wire w (0..5) -> lane bit (5-w);
// wires 6..9 -> reg bits 3..0. amp = prod of column-0 entries.
__device__ __forceinline__ void init_product(v2 (&s)[16], const float4* wmat,
                                             float cx, float sx, int lane) {
  v2 u0, u1;
#define C0(i) { float4 wa = wmat[(i) * 2], wb = wmat[(i) * 2 + 1]; \
    v2 wa0 = {wa.x, wa.y}, wa1 = {wa.z, wa.w}; \
    v2 wb0 = {wb.x, wb.y}, wb1 = {wb.z, wb.w}; \
    float ca = readlane_f(cx, (i)), sa = readlane_f(sx, (i)); \
    u0 = ca * wa0 + sa * wa1; u1 = ca * wb0 + sa * wb1; }
  v2 f;
  C0(0); f = (lane & 32) ? u1 : u0;
  C0(1); f = cmul((lane & 16) ? u1 : u0, f);
  C0(2); f = cmul((lane & 8) ? u1 : u0, f);
  C0(3); f = cmul((lane & 4) ? u1 : u0, f);
  C0(4); f = cmul((lane & 2) ? u1 : u0, f);
  C0(5); f = cmul((lane & 1) ? u1 : u0, f);
  v2 q6_0, q6_1, q7_0, q7_1, q8_0, q8_1, q9_0, q9_1;
  C0(6); q6_0 = u0; q6_1 = u1;
  C0(7); q7_0 = u0; q7_1 = u1;
  C0(8); q8_0 = u0; q8_1 = u1;
  C0(9); q9_0 = u0; q9_1 = u1;
#undef C0
  // qa[(b1<<1)|b0] = v8[b1]*v9[b0] ; qb[(b3<<1)|b2] = v6[b3]*v7[b2]
  v2 qa0 = cmul(q8_0, q9_0), qa1 = cmul(q8_0, q9_1);
  v2 qa2 = cmul(q8_1, q9_0), qa3 = cmul(q8_1, q9_1);
  v2 qb0 = cmul(q6_0, q7_0), qb1 = cmul(q6_0, q7_1);
  v2 qb2 = cmul(q6_1, q7_0), qb3 = cmul(q6_1, q7_1);
  v2 fa0 = cmul(qa0, f), fa1 = cmul(qa1, f), fa2 = cmul(qa2, f), fa3 = cmul(qa3, f);
  s[0]  = cmul(qb0, fa0); s[1]  = cmul(qb0, fa1); s[2]  = cmul(qb0, fa2); s[3]  = cmul(qb0, fa3);
  s[4]  = cmul(qb1, fa0); s[5]  = cmul(qb1, fa1); s[6]  = cmul(qb1, fa2); s[7]  = cmul(qb1, fa3);
  s[8]  = cmul(qb2, fa0); s[9]  = cmul(qb2, fa1); s[10] = cmul(qb2, fa2); s[11] = cmul(qb2, fa3);
  s[12] = cmul(qb3, fa0); s[13] = cmul(qb3, fa1); s[14] = cmul(qb3, fa2); s[15] = cmul(qb3, fa3);
}

template<int L, bool PEND>
__device__ __forceinline__ void layer_gates(v2 (&s)[16], const float4* wmat,
                                            float cxv, float sxv, int lane) {
#define FUSED(i, SW) { \
    float4 wa = wmat[(L * NQ + (i)) * 2], wb = wmat[(L * NQ + (i)) * 2 + 1]; \
    float ca = readlane_f(cxv, (i)); \
    float sa = readlane_f(sxv, (i)); \
    v2 wa0 = {wa.x, wa.y}, wa1 = {wa.z, wa.w}; \
    v2 wb0 = {wb.x, wb.y}, wb1 = {wb.z, wb.w}; \
    v2 u00 = ca * wa0 + sa * wa1, u01 = ca * wa1 - sa * wa0; \
    v2 u10 = ca * wb0 + sa * wb1, u11 = ca * wb1 - sa * wb0; \
    apply_u<9 - (i), SW>(s, u00, u01, u10, u11, lane); }
  FUSED(0, PEND)            // wire0 = bit9 = lane xor 32; consumes pending swap
  FUSED(1, false) FUSED(2, false) FUSED(3, false) FUSED(4, false)
  FUSED(5, false) FUSED(6, false) FUSED(7, false) FUSED(8, false) FUSED(9, false)
#undef FUSED
}

__global__ __launch_bounds__(256, 6) void qsim(const float* __restrict__ x,
                                               const float* __restrict__ w,
                                               float* __restrict__ out, int batch) {
  // Batch-shared fused weight matrices W = RZ(w2)*RY(w1)*RZ(w0).
  __shared__ float4 wmat[NL * NQ * 2];
  int tid = threadIdx.x;
  if (tid < NL * NQ) {
    const float* wp = &w[tid * 3];
    float t0 = 0.5f * wp[0], t1 = 0.5f * wp[1], t2 = 0.5f * wp[2];
    float c1, s1; sincosf(t1, &s1, &c1);
    float cA, sA; sincosf(t0 + t2, &sA, &cA);
    float cB, sB; sincosf(t0 - t2, &sB, &cB);
    wmat[tid * 2]     = make_float4(c1 * cA, -c1 * sA, -s1 * cB, -s1 * sB);
    wmat[tid * 2 + 1] = make_float4(s1 * cB, -s1 * sB,  c1 * cA,  c1 * sA);
  }
  __syncthreads();

  int lane = tid & 63;
  int b = blockIdx.x * 4 + (tid >> 6);
  if (b >= batch) return;

  float cxv = 1.0f, sxv = 0.0f;
  if (lane < NQ) {
    float th = tanhf(x[b * NQ + lane]) * PI_F;
    sincosf(0.5f * th, &sxv, &cxv);
  }

  // Composed lane-permutation for the 5 lane-lane CNOTs.
  int srcl4;
  {
    int t = lane;
    t ^= (t >> 1) & 1;
    t ^= ((t >> 2) & 1) << 1;
    t ^= ((t >> 3) & 1) << 2;
    t ^= ((t >> 4) & 1) << 3;
    t ^= ((t >> 5) & 1) << 4;
    srcl4 = t << 2;
  }

  v2 s[16];
  // Layer 0 single-qubit part: direct product state (|0> start), then CNOTs.
  init_product(s, wmat, cxv, sxv, lane);
  cnot_block(s, lane, srcl4);

  layer_gates<1, true>(s, wmat, cxv, sxv, lane);
  cnot_block(s, lane, srcl4);
  layer_gates<2, true>(s, wmat, cxv, sxv, lane);
  cnot_block(s, lane, srcl4);
  layer_gates<3, true>(s, wmat, cxv, sxv, lane);
  cnot_block(s, lane, srcl4);
  // Layer 3's (0,9) still pending: odd regs' amps live at lane^32.

  // Measurement. q=0 (lane bit 5) sign fix for pending swap: totE - totO.
  float prob[16];
  float totE = 0.0f, totO = 0.0f;
#pragma unroll
  for (int r = 0; r < 16; ++r) {
    prob[r] = s[r].x * s[r].x + s[r].y * s[r].y;
    if (r & 1) totO += prob[r]; else totE += prob[r];
  }
  float total = totE + totO;
  float part[10];
#pragma unroll
  for (int p = 0; p < 4; ++p) {
    float acc = 0.0f;
#pragma unroll
    for (int r = 0; r < 16; ++r)
      acc += (r & (1 << p)) ? -prob[r] : prob[r];
    part[p] = acc;
  }
#pragma unroll
  for (int p = 4; p < 9; ++p)
    part[p] = (lane & (1 << (p - 4))) ? -total : total;
  {
    float d = totE - totO;             // pending xor-32 on odd regs
    part[9] = (lane & 32) ? -d : d;
  }

#pragma unroll
  for (int p = 0; p < 10; ++p) {
    float a = part[p];
    a += lxor<1>(a);
    a += lxor<2>(a);
    a += lxor<4>(a);
    a += lxor<8>(a);
    a += lxor<16>(a);
    a += lxor<32>(a);
    part[p] = a;
  }

  if (lane == 0) {
#pragma unroll
    for (int q = 0; q < NQ; ++q)
      out[b * NQ + q] = part[9 - q];
  }
}

}  // namespace

extern "C" void kernel_launch(void* const* d_in, const int* in_sizes, int n_in,
                              void* d_out, int out_size, void* d_ws, size_t ws_size,
                              hipStream_t stream) {
  const float* x = (const float*)d_in[0];
  const float* w = (const float*)d_in[1];
  float* out = (float*)d_out;
  int batch = in_sizes[0] / NQ;
  int blocks = (batch + 3) / 4;  // 4 waves/block, 1 batch element per wave
  qsim<<<blocks, 256, 0, stream>>>(x, w, out, batch);
}